// Round 5
// baseline (12297.655 us; speedup 1.0000x reference)
//
#include <hip/hip_runtime.h>
#include <hip/hip_bf16.h>

constexpr int CB = 64;     // batch
constexpr int CS = 512;    // seq
constexpr int CDE = 384;   // embed dim
constexpr int CD = 1024;   // model dim
constexpr int CM = 16;     // hist depth
constexpr int CH = 4;      // neuron hidden
constexpr int CNH = 8;     // heads
constexpr int CDH = 128;   // head dim
constexpr int CDA = 512;
constexpr int CDO = 512;
constexpr int CT = 16;     // T_MAX
constexpr int CTP1 = 17;
constexpr int NBLK = 256;  // mega-kernel grid (co-resident on 256 CUs)

typedef __attribute__((ext_vector_type(8))) short bfrag;   // 8 bf16 (4 VGPRs)
typedef __attribute__((ext_vector_type(4))) float ffrag;   // MFMA accumulator

__device__ __forceinline__ float gelu_exact(float x) {
    return 0.5f * x * (1.0f + erff(x * 0.70710678118654752440f));
}
__device__ __forceinline__ float softplusf(float x) {
    return fmaxf(x, 0.0f) + log1pf(expf(-fabsf(x)));
}
__device__ __forceinline__ float us2f(unsigned short u) {
    union { unsigned int i; float f; } c; c.i = ((unsigned int)u) << 16; return c.f;
}
__device__ __forceinline__ unsigned short f2us(float x) {
    __hip_bfloat16 b = __float2bfloat16(x);  // RNE
    union { __hip_bfloat16 b; unsigned short u; } c; c.b = b; return c.u;
}

template <typename T>
__device__ __forceinline__ float4 ld4(const T* p);
template <>
__device__ __forceinline__ float4 ld4<float>(const float* p) { return *(const float4*)p; }
template <>
__device__ __forceinline__ float4 ld4<unsigned short>(const unsigned short* p) {
    ushort4 u = *(const ushort4*)p;
    return make_float4(us2f(u.x), us2f(u.y), us2f(u.z), us2f(u.w));
}
__device__ __forceinline__ void st4(float* p, float4 v) { *(float4*)p = v; }
__device__ __forceinline__ void st4(unsigned short* p, float4 v) {
    ushort4 u = make_ushort4(f2us(v.x), f2us(v.y), f2us(v.z), f2us(v.w));
    *(ushort4*)p = u;
}

// 8 contiguous elements -> 8 bf16 (converting if fp32 source)
__device__ __forceinline__ bfrag ld8bf(const unsigned short* p) {
    return *(const bfrag*)p;
}
__device__ __forceinline__ bfrag ld8bf(const float* p) {
    float4 a = *(const float4*)p;
    float4 b = *(const float4*)(p + 4);
    bfrag v;
    v[0] = (short)f2us(a.x); v[1] = (short)f2us(a.y);
    v[2] = (short)f2us(a.z); v[3] = (short)f2us(a.w);
    v[4] = (short)f2us(b.x); v[5] = (short)f2us(b.y);
    v[6] = (short)f2us(b.z); v[7] = (short)f2us(b.w);
    return v;
}

// fp32 -> bf16 bulk convert (n divisible by 4)
__global__ __launch_bounds__(256) void convert_bf16_kernel(
    const float* __restrict__ src, unsigned short* __restrict__ dst, int n4) {
    int i = blockIdx.x * 256 + threadIdx.x;
    if (i < n4) {
        float4 v = *(const float4*)(src + (size_t)i * 4);
        st4(dst + (size_t)i * 4, v);
    }
}

// WqT[a][d] = Wq[d][a] (bf16 out); one-time
__global__ __launch_bounds__(256) void transpose_wq_kernel(
    const float* __restrict__ Wq, unsigned short* __restrict__ WqT) {
    int i = blockIdx.x * 256 + threadIdx.x;  // over CDA*CD
    if (i < CDA * CD) {
        int a = i / CD, d = i - a * CD;
        WqT[i] = f2us(Wq[(size_t)d * CDA + a]);
    }
}

// beff[i] = bq3[i] + sum_d Wq3[i,d] * bq[d]  (fp32, one-time)
__global__ __launch_bounds__(256) void beff_kernel(
    const float* __restrict__ Wqkv, const float* __restrict__ bq,
    const float* __restrict__ bqkv, float* __restrict__ beff) {
    int i = blockIdx.x * 256 + threadIdx.x;
    if (i < CD) {
        const float* w = Wqkv + (size_t)i * CD;
        float s = bqkv[i];
        for (int d = 0; d < CD; d += 4) {
            float4 wv = *(const float4*)(w + d);
            s += wv.x * bq[d] + wv.y * bq[d + 1] + wv.z * bq[d + 2] + wv.w * bq[d + 3];
        }
        beff[i] = s;
    }
}

// ---------------------------------------------------------------------------
// MFMA GEMM: C[M,N](bf16) = A[M,K] @ W[N,K]^T + bias.  128x128 tile.
// XOR-swizzled LDS (chunk ^= row&7): measured 0 bank conflicts.
// ---------------------------------------------------------------------------
template <typename TA, typename TW>
__global__ __launch_bounds__(256) void gemm_mfma(
    const TA* __restrict__ A, const TW* __restrict__ W,
    const float* __restrict__ bias, unsigned short* __restrict__ C,
    int N, int K) {
    __shared__ __align__(16) char smem[32768];
    char* As = smem;
    char* Bs = smem + 16384;
    const int tid = threadIdx.x;
    const int row0 = blockIdx.x << 7;
    const int col0 = blockIdx.y << 7;
    const int lane = tid & 63;
    const int wid = tid >> 6;
    const int wr = wid >> 1, wc = wid & 1;
    const int srow_l = tid >> 3;
    const int schunk = tid & 7;

    ffrag acc[4][4];
#pragma unroll
    for (int m = 0; m < 4; m++)
#pragma unroll
        for (int n = 0; n < 4; n++) acc[m][n] = (ffrag)0.0f;

    for (int k0 = 0; k0 < K; k0 += 64) {
        bfrag va[4], vb[4];
#pragma unroll
        for (int i = 0; i < 4; i++) {
            int r = i * 32 + srow_l;
            va[i] = ld8bf(A + (size_t)(row0 + r) * K + k0 + schunk * 8);
            vb[i] = ld8bf(W + (size_t)(col0 + r) * K + k0 + schunk * 8);
        }
#pragma unroll
        for (int i = 0; i < 4; i++) {
            int r = i * 32 + srow_l;
            int pc = schunk ^ (r & 7);
            *(bfrag*)(As + r * 128 + pc * 16) = va[i];
            *(bfrag*)(Bs + r * 128 + pc * 16) = vb[i];
        }
        __syncthreads();
#pragma unroll
        for (int s = 0; s < 2; s++) {
            bfrag af[4], bf[4];
#pragma unroll
            for (int m = 0; m < 4; m++) {
                int r = wr * 64 + m * 16 + (lane & 15);
                int chunk = (s * 4 + (lane >> 4)) ^ (r & 7);
                af[m] = *(const bfrag*)(As + r * 128 + chunk * 16);
            }
#pragma unroll
            for (int n = 0; n < 4; n++) {
                int r = wc * 64 + n * 16 + (lane & 15);
                int chunk = (s * 4 + (lane >> 4)) ^ (r & 7);
                bf[n] = *(const bfrag*)(Bs + r * 128 + chunk * 16);
            }
#pragma unroll
            for (int m = 0; m < 4; m++)
#pragma unroll
                for (int n = 0; n < 4; n++)
                    acc[m][n] = __builtin_amdgcn_mfma_f32_16x16x32_bf16(
                        af[m], bf[n], acc[m][n], 0, 0, 0);
        }
        __syncthreads();
    }

#pragma unroll
    for (int n = 0; n < 4; n++) {
        int col = col0 + wc * 64 + n * 16 + (lane & 15);
        float bv = bias[col];
#pragma unroll
        for (int m = 0; m < 4; m++) {
            int rbase = row0 + wr * 64 + m * 16 + ((lane >> 4) << 2);
#pragma unroll
            for (int j = 0; j < 4; j++) {
                C[(size_t)(rbase + j) * N + col] = f2us(acc[m][n][j] + bv);
            }
        }
    }
}

// LayerNorm + GELU, in place on bf16 h rows.
__global__ __launch_bounds__(256) void ln_gelu_kernel(
    unsigned short* __restrict__ hc, const float* __restrict__ g,
    const float* __restrict__ bb) {
    __shared__ float sred[4];
    const int tid = threadIdx.x;
    size_t base = (size_t)blockIdx.x * CD;
    float4 x = ld4(hc + base + tid * 4);
    float s = x.x + x.y + x.z + x.w;
#pragma unroll
    for (int off = 32; off; off >>= 1) s += __shfl_down(s, off, 64);
    if ((tid & 63) == 0) sred[tid >> 6] = s;
    __syncthreads();
    float mu = (sred[0] + sred[1] + sred[2] + sred[3]) * (1.0f / 1024.0f);
    float d0 = x.x - mu, d1 = x.y - mu, d2 = x.z - mu, d3 = x.w - mu;
    float sq = d0 * d0 + d1 * d1 + d2 * d2 + d3 * d3;
    __syncthreads();
#pragma unroll
    for (int off = 32; off; off >>= 1) sq += __shfl_down(sq, off, 64);
    if ((tid & 63) == 0) sred[tid >> 6] = sq;
    __syncthreads();
    float var = (sred[0] + sred[1] + sred[2] + sred[3]) * (1.0f / 1024.0f);
    float rs = 1.0f / sqrtf(var + 1e-5f);
    float4 gv = ((const float4*)g)[tid];
    float4 bv = ((const float4*)bb)[tid];
    float4 o;
    o.x = gelu_exact(d0 * rs * gv.x + bv.x);
    o.y = gelu_exact(d1 * rs * gv.y + bv.y);
    o.z = gelu_exact(d2 * rs * gv.z + bv.z);
    o.w = gelu_exact(d3 * rs * gv.w + bv.w);
    st4(hc + base + tid * 4, o);
}

// zbufT[b][d][ts]: ts=0 -> z_init[d], else 0; hist = broadcast hist_init.
__global__ __launch_bounds__(256) void init_kernel(
    const float* __restrict__ z_init, const float* __restrict__ hist_init,
    float* __restrict__ zbufT, float* __restrict__ hist) {
    int i = blockIdx.x * 256 + threadIdx.x;
    if (i < CB * CD * CTP1) {
        int rem = i % (CD * CTP1);
        int d = rem / CTP1;
        int ts = rem - d * CTP1;
        zbufT[i] = (ts == 0) ? z_init[d] : 0.0f;
    }
    if (i < CB * CD * CM) {
        hist[i] = hist_init[i % (CD * CM)];
    }
}

// ---------------------------------------------------------------------------
// Device building blocks for the phase-B mega-kernel
// ---------------------------------------------------------------------------

// 64-row x 64-col MFMA tile, full-K, register prefetch of next K-slice.
// A[64][K] bf16 row-major; W[N][K] bf16 row-major (rows col0..col0+63).
__device__ __forceinline__ void gemm_tile64(
    const unsigned short* __restrict__ A, const unsigned short* __restrict__ W,
    int K, int col0, char* As, char* Bs, ffrag acc[4]) {
    const int tid = threadIdx.x;
    const int lane = tid & 63;
    const int wv = tid >> 6;
    const int srow = tid >> 3;
    const int schunk = tid & 7;
#pragma unroll
    for (int n = 0; n < 4; n++) acc[n] = (ffrag)0.0f;
    bfrag va[2], vb[2];
#pragma unroll
    for (int i = 0; i < 2; i++) {
        int r = i * 32 + srow;
        va[i] = *(const bfrag*)(A + (size_t)r * K + schunk * 8);
        vb[i] = *(const bfrag*)(W + (size_t)(col0 + r) * K + schunk * 8);
    }
    for (int k0 = 0; k0 < K; k0 += 64) {
#pragma unroll
        for (int i = 0; i < 2; i++) {
            int r = i * 32 + srow;
            int pc = schunk ^ (r & 7);
            *(bfrag*)(As + r * 128 + pc * 16) = va[i];
            *(bfrag*)(Bs + r * 128 + pc * 16) = vb[i];
        }
        __syncthreads();
        if (k0 + 64 < K) {
#pragma unroll
            for (int i = 0; i < 2; i++) {
                int r = i * 32 + srow;
                va[i] = *(const bfrag*)(A + (size_t)r * K + (k0 + 64) + schunk * 8);
                vb[i] = *(const bfrag*)(W + (size_t)(col0 + r) * K + (k0 + 64) + schunk * 8);
            }
        }
#pragma unroll
        for (int s = 0; s < 2; s++) {
            int r = wv * 16 + (lane & 15);
            int ch = (s * 4 + (lane >> 4)) ^ (r & 7);
            bfrag af = *(const bfrag*)(As + r * 128 + ch * 16);
#pragma unroll
            for (int n = 0; n < 4; n++) {
                int r2 = n * 16 + (lane & 15);
                int ch2 = (s * 4 + (lane >> 4)) ^ (r2 & 7);
                bfrag bf = *(const bfrag*)(Bs + r2 * 128 + ch2 * 16);
                acc[n] = __builtin_amdgcn_mfma_f32_16x16x32_bf16(af, bf, acc[n], 0, 0, 0);
            }
        }
        __syncthreads();
    }
}

// attention for one (b,h) pair; smem carve: qv[128] att[512] red[4] pv[256]
__device__ __forceinline__ void attn_pair(
    int pair, const float* __restrict__ qh, const unsigned short* __restrict__ kb,
    const unsigned short* __restrict__ vb, unsigned short* __restrict__ attn_out,
    char* smraw) {
    float* qv = (float*)smraw;
    float* att = qv + 128;
    float* red = att + 512;
    float* pv = red + 4;  // [2][128]
    const int tid = threadIdx.x;
    const int b = pair >> 3, h = pair & 7;
    if (tid < CDH) qv[tid] = qh[(size_t)b * CD + h * CDH + tid];
    __syncthreads();
    const float scale = 0.08838834764831845f;  // 1/sqrt(128)
    float sc0, sc1;
    {
        const unsigned short* kr0 = kb + ((size_t)(b * CS) + tid) * CD + h * CDH;
        const unsigned short* kr1 = kr0 + (size_t)256 * CD;
        float a0 = 0.0f, a1 = 0.0f;
#pragma unroll 8
        for (int d2 = 0; d2 < CDH; d2 += 4) {
            float4 k0 = ld4(kr0 + d2);
            float4 k1 = ld4(kr1 + d2);
            a0 += k0.x * qv[d2] + k0.y * qv[d2 + 1] + k0.z * qv[d2 + 2] + k0.w * qv[d2 + 3];
            a1 += k1.x * qv[d2] + k1.y * qv[d2 + 1] + k1.z * qv[d2 + 2] + k1.w * qv[d2 + 3];
        }
        sc0 = a0 * scale;
        sc1 = a1 * scale;
    }
    float mx = fmaxf(sc0, sc1);
#pragma unroll
    for (int off = 32; off; off >>= 1) mx = fmaxf(mx, __shfl_down(mx, off, 64));
    if ((tid & 63) == 0) red[tid >> 6] = mx;
    __syncthreads();
    mx = fmaxf(fmaxf(red[0], red[1]), fmaxf(red[2], red[3]));
    float e0 = expf(sc0 - mx), e1 = expf(sc1 - mx);
    att[tid] = e0;
    att[tid + 256] = e1;
    float sm = e0 + e1;
#pragma unroll
    for (int off = 32; off; off >>= 1) sm += __shfl_down(sm, off, 64);
    __syncthreads();
    if ((tid & 63) == 0) red[tid >> 6] = sm;
    __syncthreads();
    float inv = 1.0f / (red[0] + red[1] + red[2] + red[3]);
    const int d = tid & 127, half = tid >> 7;
    const unsigned short* vr = vb + ((size_t)(b * CS) + half * 256) * CD + h * CDH + d;
    float acc = 0.0f;
#pragma unroll 4
    for (int s2 = 0; s2 < 256; s2++) {
        acc += att[half * 256 + s2] * us2f(vr[(size_t)s2 * CD]);
    }
    pv[half * 128 + d] = acc;
    __syncthreads();
    if (tid < CDH)
        attn_out[(size_t)b * CD + h * CDH + tid] = f2us((pv[tid] + pv[128 + tid]) * inv);
    __syncthreads();
}

// ---------------------------------------------------------------------------
// Phase-B mega-kernel: all 16 steps, software grid barrier between phases.
// 256 blocks x 256 threads (co-resident; 16KB LDS, <=2 blocks/CU needed).
// ---------------------------------------------------------------------------
__global__ __launch_bounds__(256) void phaseB_kernel(
    const unsigned short* __restrict__ kb, const unsigned short* __restrict__ vb,
    float* __restrict__ zbufT, float* __restrict__ hist,
    unsigned short* __restrict__ s_act, float* __restrict__ s_out,
    float* __restrict__ qh, unsigned short* __restrict__ attn_out,
    unsigned short* __restrict__ combined, unsigned short* __restrict__ pre1,
    const unsigned short* __restrict__ weff, const float* __restrict__ beff,
    const unsigned short* __restrict__ wo_b, const float* __restrict__ bo,
    const unsigned short* __restrict__ ws1_b, const float* __restrict__ bs1,
    const unsigned short* __restrict__ ws2_b, const float* __restrict__ bs2,
    const unsigned short* __restrict__ wh1_b, const float* __restrict__ bh1,
    const float* __restrict__ Wh2, const float* __restrict__ bh2,
    const float* __restrict__ decay_a, const float* __restrict__ decay_o,
    const int* __restrict__ iia, const int* __restrict__ jja,
    const int* __restrict__ iio, const int* __restrict__ jjo,
    const float* __restrict__ Wn1, const float* __restrict__ bn1,
    const float* __restrict__ Wn2, const float* __restrict__ bn2,
    const float* __restrict__ Wn3, const float* __restrict__ bn3,
    float* __restrict__ out, unsigned* __restrict__ bar) {
    __shared__ __align__(16) char smem[16384];
    char* As = smem;
    char* Bs = smem + 8192;
    const int blk = blockIdx.x;
    const int tid = threadIdx.x;
    unsigned bar_target = 0;

    auto gbar = [&]() {
        __syncthreads();
        bar_target += (unsigned)NBLK;
        if (tid == 0) {
            __threadfence();
            __hip_atomic_fetch_add(bar, 1u, __ATOMIC_RELEASE, __HIP_MEMORY_SCOPE_AGENT);
            while (__hip_atomic_load(bar, __ATOMIC_ACQUIRE, __HIP_MEMORY_SCOPE_AGENT) < bar_target) {
                __builtin_amdgcn_s_sleep(8);
            }
            __threadfence();
        }
        __syncthreads();
    };

    for (int t = 0; t < CT; t++) {
        // ---- P1: sync + z-copy into combined[:, :D] (all blocks) ----
        {
            int b = blk >> 2;
            int sg = ((blk & 3) << 8) + tid;
            const float* zbT = zbufT + (size_t)b * CD * CTP1;
            combined[(size_t)b * (2 * CD) + sg] = f2us(zbT[(size_t)sg * CTP1 + t]);
            float soft;
            int ii, jj;
            if (sg < CDA) {
                soft = softplusf(decay_a[sg]);
                ii = iia[sg]; jj = jja[sg];
            } else {
                int s2 = sg - CDA;
                soft = softplusf(decay_o[s2]);
                ii = iio[s2]; jj = jjo[s2];
            }
            const float* zi = zbT + (size_t)ii * CTP1;
            const float* zj = zbT + (size_t)jj * CTP1;
            float num = 0.0f, den = 0.0f;
            for (int ts = 0; ts <= t; ts++) {
                float w = expf(-soft * (float)(t - ts));
                num += zi[ts] * zj[ts] * w;
                den += w * w;
            }
            float val = num / sqrtf(den + 1e-8f);
            if (sg < CDA) s_act[b * CDA + sg] = f2us(val);
            else s_out[b * CDO + (sg - CDA)] = val;
        }
        gbar();

        // ---- P2: qh = s_act @ Weff^T + beff (blocks 0-15); logits (16-79) ----
        if (blk < 16) {
            ffrag acc[4];
            gemm_tile64(s_act, weff, CDA, blk * 64, As, Bs, acc);
            const int lane = tid & 63, wv = tid >> 6;
#pragma unroll
            for (int n = 0; n < 4; n++) {
                int col = blk * 64 + n * 16 + (lane & 15);
                float bv = beff[col];
                int b0 = wv * 16 + ((lane >> 4) << 2);
#pragma unroll
                for (int j = 0; j < 4; j++)
                    qh[(size_t)(b0 + j) * CD + col] = acc[n][j] + bv;
            }
        } else if (blk >= 16 && blk < 80) {
            int b = blk - 16;
            float* so = (float*)smem;
            float* hh = so + CDO;
            float* red = hh + CDO;
            ((float2*)so)[tid] = ((const float2*)(s_out + (size_t)b * CDO))[tid];
            __syncthreads();
#pragma unroll
            for (int p = 0; p < 2; p++) {
                int j = tid + p * 256;
                const unsigned short* w = wh1_b + (size_t)j * CDO;
                float s = bh1[j];
#pragma unroll 4
                for (int k2 = 0; k2 < CDO; k2 += 4) {
                    float4 wv = ld4(w + k2);
                    s += wv.x * so[k2] + wv.y * so[k2 + 1] + wv.z * so[k2 + 2] + wv.w * so[k2 + 3];
                }
                hh[j] = gelu_exact(s);
            }
            __syncthreads();
            float part = hh[tid] * Wh2[tid] + hh[tid + 256] * Wh2[tid + 256];
#pragma unroll
            for (int off = 32; off; off >>= 1) part += __shfl_down(part, off, 64);
            if ((tid & 63) == 0) red[tid >> 6] = part;
            __syncthreads();
            if (tid == 0) out[b * CT + t] = red[0] + red[1] + red[2] + red[3] + bh2[0];
        }
        gbar();

        // ---- P3: attention, 512 pairs over 256 blocks ----
        attn_pair(2 * blk, qh, kb, vb, attn_out, smem);
        attn_pair(2 * blk + 1, qh, kb, vb, attn_out, smem);
        gbar();

        // ---- P4: combined[:, D:] = attn_out @ Wo^T + bo (blocks 0-15) ----
        if (blk < 16) {
            ffrag acc[4];
            gemm_tile64(attn_out, wo_b, CD, blk * 64, As, Bs, acc);
            const int lane = tid & 63, wv = tid >> 6;
#pragma unroll
            for (int n = 0; n < 4; n++) {
                int col = blk * 64 + n * 16 + (lane & 15);
                float bv = bo[col];
                int b0 = wv * 16 + ((lane >> 4) << 2);
#pragma unroll
                for (int j = 0; j < 4; j++)
                    combined[(size_t)(b0 + j) * (2 * CD) + CD + col] = f2us(acc[n][j] + bv);
            }
        }
        gbar();

        // ---- P5: pre1 = gelu(combined @ Ws1^T + bs1) (blocks 0-31) ----
        if (blk < 32) {
            ffrag acc[4];
            gemm_tile64(combined, ws1_b, 2 * CD, blk * 64, As, Bs, acc);
            const int lane = tid & 63, wv = tid >> 6;
#pragma unroll
            for (int n = 0; n < 4; n++) {
                int col = blk * 64 + n * 16 + (lane & 15);
                float bv = bs1[col];
                int b0 = wv * 16 + ((lane >> 4) << 2);
#pragma unroll
                for (int j = 0; j < 4; j++)
                    pre1[(size_t)(b0 + j) * (2 * CD) + col] = f2us(gelu_exact(acc[n][j] + bv));
            }
        }
        gbar();

        // ---- P6: pre = pre1 @ Ws2^T + bs2, fused neuron MLP -> zbufT[:,:,t+1] ----
        if (blk < 16) {
            ffrag acc[4];
            gemm_tile64(pre1, ws2_b, 2 * CD, blk * 64, As, Bs, acc);
            const int lane = tid & 63, wv = tid >> 6;
#pragma unroll
            for (int n = 0; n < 4; n++) {
                int d = blk * 64 + n * 16 + (lane & 15);
                float bv = bs2[d];
                int b0 = wv * 16 + ((lane >> 4) << 2);
#pragma unroll
                for (int j = 0; j < 4; j++) {
                    int b = b0 + j;
                    float prev = acc[n][j] + bv;
                    int idx = b * CD + d;
                    float hv[CM];
                    float* hp = hist + (size_t)idx * CM;
#pragma unroll
                    for (int m = 0; m < CM - 1; m++) hv[m] = hp[m + 1];
                    hv[CM - 1] = prev;
#pragma unroll
                    for (int m = 0; m < CM; m++) hp[m] = hv[m];
                    float x1[CH];
#pragma unroll
                    for (int hh2 = 0; hh2 < CH; hh2++) {
                        const float* w = Wn1 + ((size_t)d * CH + hh2) * CM;
                        float s = bn1[d * CH + hh2];
#pragma unroll
                        for (int m = 0; m < CM; m++) s += hv[m] * w[m];
                        x1[hh2] = gelu_exact(s);
                    }
                    float x2[CH];
#pragma unroll
                    for (int g = 0; g < CH; g++) {
                        float s = bn2[d * CH + g];
#pragma unroll
                        for (int hh2 = 0; hh2 < CH; hh2++)
                            s += x1[hh2] * Wn2[((size_t)d * CH + g) * CH + hh2];
                        x2[g] = gelu_exact(s);
                    }
                    float z = bn3[d];
#pragma unroll
                    for (int hh2 = 0; hh2 < CH; hh2++) z += x2[hh2] * Wn3[d * CH + hh2];
                    zbufT[(size_t)idx * CTP1 + (t + 1)] = z;
                }
            }
        }
        gbar();
    }
}

// Writes v to all outputs; v encodes ws_size in MB so a failure is decodable.
__global__ void sentinel_kernel(float* out, float v) {
    int i = blockIdx.x * 256 + threadIdx.x;
    if (i < CB * CT) out[i] = v;
}

extern "C" void kernel_launch(void* const* d_in, const int* in_sizes, int n_in,
                              void* d_out, int out_size, void* d_ws, size_t ws_size,
                              hipStream_t stream) {
    const float* emb = (const float*)d_in[0];
    const float* Wp = (const float*)d_in[1];
    const float* bp = (const float*)d_in[2];
    const float* ln_g = (const float*)d_in[3];
    const float* ln_b = (const float*)d_in[4];
    const float* decay_a = (const float*)d_in[5];
    const float* decay_o = (const float*)d_in[6];
    const float* Wq = (const float*)d_in[7];
    const float* bq = (const float*)d_in[8];
    const float* Wqkv = (const float*)d_in[9];
    const float* bqkv = (const float*)d_in[10];
    const float* Wo = (const float*)d_in[11];
    const float* bo = (const float*)d_in[12];
    const float* Ws1 = (const float*)d_in[13];
    const float* bs1 = (const float*)d_in[14];
    const float* Ws2 = (const float*)d_in[15];
    const float* bs2 = (const float*)d_in[16];
    const float* Wn1 = (const float*)d_in[17];
    const float* bn1 = (const float*)d_in[18];
    const float* Wn2 = (const float*)d_in[19];
    const float* bn2 = (const float*)d_in[20];
    const float* Wn3 = (const float*)d_in[21];
    const float* bn3 = (const float*)d_in[22];
    const float* Wh1 = (const float*)d_in[23];
    const float* bh1 = (const float*)d_in[24];
    const float* Wh2 = (const float*)d_in[25];
    const float* bh2 = (const float*)d_in[26];
    const float* z_init = (const float*)d_in[27];
    const float* hist_init = (const float*)d_in[28];
    const int* iia = (const int*)d_in[29];
    const int* jja = (const int*)d_in[30];
    const int* iio = (const int*)d_in[31];
    const int* jjo = (const int*)d_in[32];
    float* out = (float*)d_out;

    char* wsb = (char*)d_ws;
    size_t off = 0;
    auto alloc = [&](size_t bytes) {
        void* p = wsb + off;
        off += (bytes + 255) & ~(size_t)255;
        return p;
    };
    unsigned short* ctx  = (unsigned short*)alloc((size_t)CB * CS * CD * 2);
    unsigned short* kbuf = (unsigned short*)alloc((size_t)CB * CS * CD * 2);
    unsigned short* vbuf = (unsigned short*)alloc((size_t)CB * CS * CD * 2);
    float* zbufT = (float*)alloc((size_t)CB * CD * CTP1 * 4);
    float* hist = (float*)alloc((size_t)CB * CD * CM * 4);
    unsigned short* s_act = (unsigned short*)alloc((size_t)CB * CDA * 2);
    float* s_out = (float*)alloc((size_t)CB * CDO * 4);
    float* qh = (float*)alloc((size_t)CB * CD * 4);
    unsigned short* attn_out = (unsigned short*)alloc((size_t)CB * CD * 2);
    unsigned short* combined = (unsigned short*)alloc((size_t)CB * 2 * CD * 2);
    unsigned short* pre1 = (unsigned short*)alloc((size_t)CB * 2 * CD * 2);
    // bf16 weights
    unsigned short* wqkv_b = (unsigned short*)alloc((size_t)3 * CD * CD * 2);
    unsigned short* wo_b = (unsigned short*)alloc((size_t)CD * CD * 2);
    unsigned short* ws1_b = (unsigned short*)alloc((size_t)2 * CD * 2 * CD * 2);
    unsigned short* ws2_b = (unsigned short*)alloc((size_t)CD * 2 * CD * 2);
    unsigned short* wh1_b = (unsigned short*)alloc((size_t)CDO * CDO * 2);
    unsigned short* wqT_b = (unsigned short*)alloc((size_t)CDA * CD * 2);
    unsigned short* weff_b = (unsigned short*)alloc((size_t)CD * CDA * 2);
    float* beff = (float*)alloc((size_t)CD * 4);
    float* zbias = (float*)alloc((size_t)CDA * 4);
    unsigned* bar = (unsigned*)alloc(256);

    if (off > ws_size) {
        sentinel_kernel<<<dim3(4), dim3(256), 0, stream>>>(out, -(float)(ws_size >> 20));
        return;
    }

    // ---- One-time setup: bf16 weights, Weff = Wq3@Wq, beff ----
    auto conv = [&](const float* s, unsigned short* d, size_t n) {
        int n4 = (int)(n / 4);
        convert_bf16_kernel<<<dim3((n4 + 255) / 256), 256, 0, stream>>>(s, d, n4);
    };
    conv(Wqkv, wqkv_b, (size_t)3 * CD * CD);
    conv(Wo, wo_b, (size_t)CD * CD);
    conv(Ws1, ws1_b, (size_t)2 * CD * 2 * CD);
    conv(Ws2, ws2_b, (size_t)CD * 2 * CD);
    conv(Wh1, wh1_b, (size_t)CDO * CDO);
    transpose_wq_kernel<<<dim3((CDA * CD + 255) / 256), 256, 0, stream>>>(Wq, wqT_b);
    hipMemsetAsync(zbias, 0, (size_t)CDA * 4, stream);
    hipMemsetAsync(bar, 0, 4, stream);
    // Weff[i,a] = sum_d Wq3[i,d] Wq[d,a]:  C = Wq3 @ WqT^T  (M=1024, N=512, K=1024)
    gemm_mfma<unsigned short, unsigned short><<<dim3(CD / 128, CDA / 128), 256, 0, stream>>>(
        wqkv_b, wqT_b, zbias, weff_b, CDA, CD);
    beff_kernel<<<dim3(4), 256, 0, stream>>>(Wqkv, bq, bqkv, beff);

    // ---- Phase A (bf16 MFMA) ----
    gemm_mfma<float, float><<<dim3(CB * CS / 128, CD / 128), 256, 0, stream>>>(
        emb, Wp, bp, ctx, CD, CDE);
    ln_gelu_kernel<<<dim3(CB * CS), 256, 0, stream>>>(ctx, ln_g, ln_b);
    gemm_mfma<unsigned short, unsigned short><<<dim3(CB * CS / 128, CD / 128), 256, 0, stream>>>(
        ctx, wqkv_b + (size_t)CD * CD, bqkv + CD, kbuf, CD, CD);
    gemm_mfma<unsigned short, unsigned short><<<dim3(CB * CS / 128, CD / 128), 256, 0, stream>>>(
        ctx, wqkv_b + (size_t)2 * CD * CD, bqkv + 2 * CD, vbuf, CD, CD);
    init_kernel<<<dim3(4352), 256, 0, stream>>>(z_init, hist_init, zbufT, hist);

    // ---- Phase B: one persistent mega-kernel, 16 steps, 6 grid barriers/step ----
    phaseB_kernel<<<dim3(NBLK), dim3(256), 0, stream>>>(
        kbuf, vbuf, zbufT, hist, s_act, s_out, qh, attn_out, combined, pre1,
        weff_b, beff, wo_b, bo, ws1_b, bs1, ws2_b, bs2, wh1_b, bh1, Wh2, bh2,
        decay_a, decay_o, iia, jja, iio, jjo,
        Wn1, bn1, Wn2, bn2, Wn3, bn3, out, bar);
}